// Round 1
// baseline (87.043 us; speedup 1.0000x reference)
//
#include <hip/hip_runtime.h>
#include <cmath>

#define T_STEPS 384
#define CH 64
#define NCH 6

__device__ __forceinline__ float readlane_f(float v, int l) {
    return __int_as_float(__builtin_amdgcn_readlane(__float_as_int(v), l));
}

// One wave (64 lanes) per neuron. Lane l owns step cb+l of the current
// 64-step chunk. u_l = c2 + c3*I_l - mem_l accumulates the (negated) memory
// term: far field gathered from LDS delta history at chunk start, near field
// scattered forward each step via a zero-padded weight table (no masking).
// The per-step broadcast uses v_readlane (VALU latency), not shuffles.
__global__ __launch_bounds__(64)
void flif_kernel(const float* __restrict__ I_old, const float* __restrict__ W,
                 float* __restrict__ out, float c1, float c2, float c3, int Stot)
{
    const int s    = blockIdx.x;
    const int lane = threadIdx.x;
    if (s >= Stot) return;

    __shared__ __align__(16) float wtab[T_STEPS];  // wtab[a] = wr[a] = W[4999-a], wtab[0]=0
    __shared__ float ltab[2 * CH];                 // ltab[63+a] = wr[a] for a=1..63, else 0
    __shared__ __align__(16) float dbuf[T_STEPS];  // delta history (dbuf[0] forced to 0)

    const float* Irow = I_old + (size_t)s * T_STEPS;
    float Inext = Irow[lane];                      // prefetch chunk-0 I early

    for (int a = lane; a < T_STEPS; a += 64)
        wtab[a] = a ? W[4999 - a] : 0.0f;
    ltab[lane] = 0.0f;                             // indices 0..63 -> 0 (l - i <= 0)
    ltab[64 + lane] = (lane < 63) ? W[4998 - lane] : 0.0f;  // ltab[63+a] = wr[a]
    __syncthreads();

    float* out_spk = out + (size_t)s * T_STEPS;
    float* out_trc = out + (size_t)Stot * T_STEPS + (size_t)s * T_STEPS;

    float V = 0.0f;   // uniform across all lanes at all times

    for (int c = 0; c < NCH; ++c) {
        const int cb = c * CH;
        const float Ic = Inext;
        if (c + 1 < NCH) Inext = Irow[cb + CH + lane];   // prefetch next chunk

        // ---- far field: acc = sum_{j<cb} dbuf[j] * wr[(cb+lane) - j] ----
        float acc = 0.0f;
        for (int j = 0; j < cb; j += 4) {
            const float4 d4 = *reinterpret_cast<const float4*>(&dbuf[j]); // uniform addr -> b128 broadcast
            const int b = cb + lane - j;                                   // >= lane+1, <= 383
            acc += d4.x * wtab[b];
            acc += d4.y * wtab[b - 1];
            acc += d4.z * wtab[b - 2];
            acc += d4.w * wtab[b - 3];
        }

        float u = fmaf(c3, Ic, c2) - acc;   // t_n pre-seeded with -far; near scattered below
        const float Vs = V;                 // V entering this chunk (= trace[cb-1], or 0)
        float tc = 0.0f;                    // lane i captures trace of step cb+i

        auto step = [&](int i) {
            const float w  = ltab[lane + 63 - i];     // wr[lane-i], 0 for lane<=i
            const float t  = readlane_f(u, i);        // c2 + c3*I_n - mem_n  (scalar)
            const float V2 = fmaf(c1, V, t);          // V2 = (1-COEF*GL)*V + t
            const float Vn = V2 - ((V > -50.0f) ? 20.0f : 0.0f);  // spike uses PREVIOUS V
            const float d  = Vn - V;
            u = fmaf(-w, d, u);                       // forward-scatter delta into future lanes
            if (lane == i) tc = Vn;
            V = Vn;
        };

        if (c == 0) {
            {   // step 0: V_prev=0 -> spike=1, V_pre=-70, V_new=-90; delta masked out
                V = -90.0f;
                if (lane == 0) tc = V;
            }
            {   // step 1: V1 rule, no memory term
                const float I1 = readlane_f(Ic, 1);
                const float V1 = fmaf(0.005f, (I1 / 0.025f) - V, V);
                const float Vn = (V > -50.0f) ? (V1 - 20.0f) : V1;   // V=-90 -> no reset
                const float d  = Vn - V;
                u = fmaf(-ltab[lane + 62], d, u);     // scatter delta_1
                if (lane == 1) tc = Vn;
                V = Vn;
            }
            #pragma unroll
            for (int i = 2; i < CH; ++i) step(i);
        } else {
            #pragma unroll
            for (int i = 0; i < CH; ++i) step(i);
        }

        // ---- chunk epilogue: reconstruct prev-V per lane -> spike, delta ----
        float prev = __shfl_up(tc, 1);
        if (lane == 0) prev = Vs;
        const float spk = (prev > -50.0f) ? 1.0f : 0.0f;
        float d = tc - prev;
        if (c == 0 && lane == 0) d = 0.0f;            // delta_0 excluded by reference mask
        dbuf[cb + lane] = d;
        out_spk[cb + lane] = spk;
        out_trc[cb + lane] = tc;
        __syncthreads();
    }
}

extern "C" void kernel_launch(void* const* d_in, const int* in_sizes, int n_in,
                              void* d_out, int out_size, void* d_ws, size_t ws_size,
                              hipStream_t stream) {
    const float* I = (const float*)d_in[0];
    const float* W = (const float*)d_in[1];
    float* out = (float*)d_out;
    const int S = in_sizes[0] / T_STEPS;   // 2048

    // Constants in host double, exactly mirroring the Python reference, then
    // cast to f32 (JAX weak-types the Python scalars to f32 in the kernel).
    const double COEF = std::pow(0.1, 0.15) * std::tgamma(1.85) / 0.5;
    const float c3 = (float)COEF;                      // COEF
    const float c1 = (float)(1.0 - COEF * 0.025);      // 1 - COEF*GL
    const float c2 = (float)(COEF * 0.025 * -70.0);    // COEF*GL*VL

    flif_kernel<<<S, 64, 0, stream>>>(I, W, out, c1, c2, c3, S);
}